// Round 1
// baseline (202.703 us; speedup 1.0000x reference)
//
#include <hip/hip_runtime.h>
#include <math.h>

// S4 DPLR kernel + batched causal convolution via custom packed-real FFTs.
//
//  A) s4_khat_kernel : K_hat[l], l=0..4096, fp64, stable Cauchy form
//       c*inv = 2 / (20(1-w) - (1+w)*Lambda)  (cancels l=4096 singularity)
//  B) s4_prep_kernel : one workgroup.
//       phase1: K = irfft_8192(K_hat) via packed complex IFFT-4096 (K stays in LDS)
//       phase2: Hs = rfft_16384(pad(K)) / 8192 via packed complex FFT-8192
//  C) s4_conv_kernel : per batch (1024 WGs, 64KB LDS, 2 blocks/CU):
//       pack -> DIF FFT-8192 (digit-reversed sigma order) ->
//       fused (unpack rfft -> *Hs -> repack) in sigma order -> DIT IFFT -> y
//
// In-place mixed radix [8,8,8,8,2]; sigma(k) verified by hand on N=16 [8,2].

#define TPB 256

__device__ __forceinline__ float2 cadd(float2 a, float2 b){ return make_float2(a.x+b.x, a.y+b.y); }
__device__ __forceinline__ float2 csub(float2 a, float2 b){ return make_float2(a.x-b.x, a.y-b.y); }
__device__ __forceinline__ float2 cmulf(float2 a, float2 b){
  return make_float2(a.x*b.x - a.y*b.y, a.x*b.y + a.y*b.x);
}
template<int SGN>
__device__ __forceinline__ float2 muli(float2 v){       // SGN*i*v
  return (SGN > 0) ? make_float2(-v.y, v.x) : make_float2(v.y, -v.x);
}

template<int SGN>   // -1: forward DFT8; +1: conj (unscaled inverse)
__device__ __forceinline__ void dft8(const float2* a, float2* X){
  const float C  = 0.70710678118654752f;
  const float SC = (SGN > 0) ? C : -C;
  float2 e0=cadd(a[0],a[4]), e1=csub(a[0],a[4]);
  float2 e2=cadd(a[2],a[6]), e3=csub(a[2],a[6]);
  float2 f0=cadd(a[1],a[5]), f1=csub(a[1],a[5]);
  float2 f2=cadd(a[3],a[7]), f3=csub(a[3],a[7]);
  float2 ie3 = muli<SGN>(e3), if3 = muli<SGN>(f3);
  float2 E0=cadd(e0,e2), E2=csub(e0,e2);
  float2 E1=cadd(e1,ie3), E3=csub(e1,ie3);
  float2 O0=cadd(f0,f2), O2=csub(f0,f2);
  float2 O1=cadd(f1,if3), O3=csub(f1,if3);
  float2 O2r = muli<SGN>(O2);
  float2 O1r = cmulf(O1, make_float2(C,  SC));
  float2 O3r = cmulf(O3, make_float2(-C, SC));
  X[0]=cadd(E0,O0);  X[4]=csub(E0,O0);
  X[1]=cadd(E1,O1r); X[5]=csub(E1,O1r);
  X[2]=cadd(E2,O2r); X[6]=csub(E2,O2r);
  X[3]=cadd(E3,O3r); X[7]=csub(E3,O3r);
}

template<int NFFT>
__device__ void dif8_stage(float2* S, int size, int tid){
  const int t = size >> 3;
  const float ang = -6.283185307179586f / (float)size;
  for (int u = tid; u < (NFFT >> 3); u += TPB){
    int j = u & (t - 1);
    int base = ((u - j) << 3) + j;
    float2 a[8], X[8];
#pragma unroll
    for (int q = 0; q < 8; q++) a[q] = S[base + q*t];
    dft8<-1>(a, X);
    if (t > 1){
      float sn, cn; __sincosf(ang * (float)j, &sn, &cn);
      float2 w = make_float2(cn, sn), wq = w;
#pragma unroll
      for (int q = 1; q < 8; q++){ X[q] = cmulf(X[q], wq); wq = cmulf(wq, w); }
    }
#pragma unroll
    for (int q = 0; q < 8; q++) S[base + q*t] = X[q];
  }
}

template<int NFFT>
__device__ void dit8_stage(float2* S, int size, int tid){
  const int t = size >> 3;
  const float ang = 6.283185307179586f / (float)size;
  for (int u = tid; u < (NFFT >> 3); u += TPB){
    int j = u & (t - 1);
    int base = ((u - j) << 3) + j;
    float2 a[8], X[8];
#pragma unroll
    for (int q = 0; q < 8; q++) a[q] = S[base + q*t];
    if (t > 1){
      float sn, cn; __sincosf(ang * (float)j, &sn, &cn);
      float2 w = make_float2(cn, sn), wq = w;
#pragma unroll
      for (int q = 1; q < 8; q++){ a[q] = cmulf(a[q], wq); wq = cmulf(wq, w); }
    }
    dft8<1>(a, X);
#pragma unroll
    for (int q = 0; q < 8; q++) S[base + q*t] = X[q];
  }
}

template<int NFFT>
__device__ void r2_stage(float2* S, int tid){   // self-inverse, conflict-free via b128
  float4* S4 = reinterpret_cast<float4*>(S);
  for (int u = tid; u < (NFFT >> 1); u += TPB){
    float4 v = S4[u];
    S4[u] = make_float4(v.x+v.z, v.y+v.w, v.x-v.z, v.y-v.w);
  }
}

__device__ __forceinline__ int sig8192(int k){
  return ((k & 7) << 10) | (((k >> 3) & 7) << 7) | (((k >> 6) & 7) << 4)
       | (((k >> 9) & 7) << 1) | ((k >> 12) & 1);
}
__device__ __forceinline__ int sig4096(int k){
  return ((k & 7) << 9) | (((k >> 3) & 7) << 6) | (((k >> 6) & 7) << 3) | ((k >> 9) & 7);
}

__global__ void s4_khat_kernel(const float* __restrict__ Bp, const float* __restrict__ Cp,
                               float2* __restrict__ khat){
  int l = blockIdx.x * blockDim.x + threadIdx.x;
  if (l > 4096) return;
  const double PI = 3.14159265358979323846264338327950288;
  double th = (2.0 * PI / 8192.0) * (double)l;
  double wr = cos(th), wi = sin(th);
  double ux = 1.0 + wr, uy = wi;
  double vx = 1.0 - wr, vy = -wi;
  double gx = 20.0 * vx, gy = 20.0 * vy;
  double s00x=0,s00y=0, s01x=0,s01y=0, s10x=0,s10y=0, s11x=0,s11y=0;
  for (int n = 0; n < 64; n++){
    double Bn = (double)Bp[n], Cn = (double)Cp[n];
    double Pn = sqrt((double)n + 0.5);
    double lx = -0.5, ly = PI * (double)n;
    double dx = gx - (ux*lx - uy*ly);
    double dy = gy - (ux*ly + uy*lx);
    double inv2 = 2.0 / (dx*dx + dy*dy);
    double cix = dx * inv2, ciy = -dy * inv2;
    double w00 = Cn*Bn, w01 = Cn*Pn, w10 = Pn*Bn, w11 = Pn*Pn;
    s00x += w00*cix; s00y += w00*ciy;
    s01x += w01*cix; s01y += w01*ciy;
    s10x += w10*cix; s10y += w10*ciy;
    s11x += w11*cix; s11y += w11*ciy;
  }
  double hux = 0.5*ux, huy = 0.5*uy;
  double k11x = hux*s11x - huy*s11y;
  double k11y = hux*s11y + huy*s11x;
  double p1x = 1.0 + k11x, p1y = k11y;
  double t1x = s01x*p1x - s01y*p1y, t1y = s01x*p1y + s01y*p1x;
  double t2x = t1x*s10x - t1y*s10y, t2y = t1x*s10y + t1y*s10x;
  double crx = t2x*hux - t2y*huy,   cry = t2x*huy + t2y*hux;
  khat[l] = make_float2((float)(s00x - crx), (float)(s00y - cry));
}

__global__ __launch_bounds__(TPB) void s4_prep_kernel(const float2* __restrict__ khat,
                                                      float2* __restrict__ Hs){
  __shared__ __align__(16) float2 S[8192];
  const int tid = threadIdx.x;
  for (int k = tid; k < 4096; k += TPB){
    float2 Yk = khat[k];
    float2 Ymc = khat[4096 - k];
    float2 E  = make_float2(0.5f*(Yk.x + Ymc.x), 0.5f*(Yk.y - Ymc.y));
    float2 Bd = make_float2(0.5f*(Yk.x - Ymc.x), 0.5f*(Yk.y + Ymc.y));
    float sn, cn; __sincosf(7.669903939428206e-4f * (float)k, &sn, &cn);
    float2 O = cmulf(make_float2(cn, sn), Bd);
    S[sig4096(k)] = make_float2((E.x - O.y) * (1.0f/4096.0f),
                                (E.y + O.x) * (1.0f/4096.0f));
  }
  __syncthreads();
  dit8_stage<4096>(S, 8, tid);    __syncthreads();
  dit8_stage<4096>(S, 64, tid);   __syncthreads();
  dit8_stage<4096>(S, 512, tid);  __syncthreads();
  dit8_stage<4096>(S, 4096, tid); __syncthreads();
  for (int n = 4096 + tid; n < 8192; n += TPB) S[n] = make_float2(0.f, 0.f);
  __syncthreads();
  dif8_stage<8192>(S, 8192, tid); __syncthreads();
  dif8_stage<8192>(S, 1024, tid); __syncthreads();
  dif8_stage<8192>(S, 128, tid);  __syncthreads();
  dif8_stage<8192>(S, 16, tid);   __syncthreads();
  r2_stage<8192>(S, tid);         __syncthreads();
  for (int k = tid; k <= 4096; k += TPB){
    int j = (8192 - k) & 8191;
    float2 Zk = S[sig8192(k)], Zj = S[sig8192(j)];
    float2 A  = make_float2(0.5f*(Zk.x + Zj.x), 0.5f*(Zk.y - Zj.y));
    float2 Bc = make_float2(0.5f*(Zk.x - Zj.x), 0.5f*(Zk.y + Zj.y));
    float sn, cn; __sincosf(-3.834951969714103e-4f * (float)k, &sn, &cn);
    float2 tb  = cmulf(make_float2(cn, sn), Bc);
    float2 tcb = cmulf(make_float2(cn, -sn), make_float2(Bc.x, -Bc.y));
    const float s = 1.0f / 8192.0f;
    float2 Xk = make_float2((A.x + tb.y) * s,  (A.y - tb.x) * s);
    float2 Xm = make_float2((A.x + tcb.y) * s, (-A.y - tcb.x) * s);
    Hs[k] = Xk;
    if (k == 0) Hs[8192] = Xm;
    else if (k != 4096) Hs[8192 - k] = Xm;
  }
}

__global__ __launch_bounds__(TPB) void s4_conv_kernel(const float2* __restrict__ x2,
                                                      const float2* __restrict__ Hs,
                                                      float2* __restrict__ y2){
  __shared__ __align__(16) float2 S[8192];
  const int tid = threadIdx.x;
  const int b = blockIdx.x;
  const float2* xb = x2 + (size_t)b * 4096;
  for (int n = tid; n < 4096; n += TPB) S[n] = xb[n];
  for (int n = 4096 + tid; n < 8192; n += TPB) S[n] = make_float2(0.f, 0.f);
  __syncthreads();
  dif8_stage<8192>(S, 8192, tid); __syncthreads();
  dif8_stage<8192>(S, 1024, tid); __syncthreads();
  dif8_stage<8192>(S, 128, tid);  __syncthreads();
  dif8_stage<8192>(S, 16, tid);   __syncthreads();
  r2_stage<8192>(S, tid);         __syncthreads();
  for (int k = tid; k <= 4096; k += TPB){
    int j = (8192 - k) & 8191;
    int sk = sig8192(k), sj = sig8192(j);
    float2 Zk = S[sk], Zj = S[sj];
    float2 A  = make_float2(0.5f*(Zk.x + Zj.x), 0.5f*(Zk.y - Zj.y));
    float2 Bc = make_float2(0.5f*(Zk.x - Zj.x), 0.5f*(Zk.y + Zj.y));
    float sn, cn; __sincosf(-3.834951969714103e-4f * (float)k, &sn, &cn);
    float2 tb  = cmulf(make_float2(cn, sn), Bc);
    float2 tcb = cmulf(make_float2(cn, -sn), make_float2(Bc.x, -Bc.y));
    float2 Xk = make_float2(A.x + tb.y,  A.y - tb.x);
    float2 Xm = make_float2(A.x + tcb.y, -A.y - tcb.x);
    float2 Yk = cmulf(Xk, Hs[k]);
    float2 Ym = cmulf(Xm, Hs[8192 - k]);
    float2 E = make_float2(0.5f*(Yk.x + Ym.x), 0.5f*(Yk.y - Ym.y));
    float2 D = make_float2(0.5f*(Yk.x - Ym.x), 0.5f*(Yk.y + Ym.y));
    float2 Od = cmulf(make_float2(cn, -sn), D);
    S[sk] = make_float2(E.x - Od.y, E.y + Od.x);
    if (k != 0 && k != 4096)
      S[sj] = make_float2(E.x + Od.y, Od.x - E.y);
  }
  __syncthreads();
  r2_stage<8192>(S, tid);         __syncthreads();
  dit8_stage<8192>(S, 16, tid);   __syncthreads();
  dit8_stage<8192>(S, 128, tid);  __syncthreads();
  dit8_stage<8192>(S, 1024, tid); __syncthreads();
  dit8_stage<8192>(S, 8192, tid); __syncthreads();
  float2* yb = y2 + (size_t)b * 4096;
  for (int n = tid; n < 4096; n += TPB) yb[n] = S[n];
}

extern "C" void kernel_launch(void* const* d_in, const int* in_sizes, int n_in,
                              void* d_out, int out_size, void* d_ws, size_t ws_size,
                              hipStream_t stream){
  (void)n_in; (void)out_size; (void)ws_size;
  const float* x  = (const float*)d_in[0];
  const float* Bp = (const float*)d_in[1];
  const float* Cp = (const float*)d_in[2];
  float2* khat = (float2*)d_ws;                     // 4097 float2
  float2* Hs   = (float2*)((char*)d_ws + 33280);    // 8193 float2
  const int batch = in_sizes[0] / 8192;
  hipLaunchKernelGGL(s4_khat_kernel, dim3(17), dim3(TPB), 0, stream, Bp, Cp, khat);
  hipLaunchKernelGGL(s4_prep_kernel, dim3(1), dim3(TPB), 0, stream, khat, Hs);
  hipLaunchKernelGGL(s4_conv_kernel, dim3(batch), dim3(TPB), 0, stream,
                     (const float2*)x, (const float2*)Hs, (float2*)d_out);
}

// Round 2
// 153.656 us; speedup vs baseline: 1.3192x; 1.3192x over previous
//
#include <hip/hip_runtime.h>
#include <math.h>

// S4 DPLR kernel + batched causal convolution via custom packed-real FFTs.
//
//  A) s4_khat_kernel : K_hat[l], l=0..4096, fp64, stable Cauchy form
//  B) s4_prep_kernel : one WG (1024 thr): K = irfft_8192(K_hat) (packed IFFT-4096),
//       Hs = rfft_16384(pad K)/8192 (packed FFT-8192), written as sigma-permuted
//       pair tables Ta[m]=H[k(2m)], Tb[m]=H[8192-k(2m)] for coalesced conv loads.
//  C) s4_conv_kernel : per batch (1024 WGs, 512 thr, 64KB LDS, 2 blk/CU):
//       pack -> DIF FFT-8192 -> pointwise (pair loop over even sigma addresses,
//       race-free perfect matching) -> DIT IFFT -> y.
//
// All LDS addresses go through SW(x) = x ^ ((x>>4)&15): a storage bijection that
// spreads every access pattern (strides 1024/128/16/2/1, sigma-scatter) to
// ~4 lanes per bank-pair (uniform). r2_stage compensates the possible pair-order
// flip with a sign trick. Verified per-stage by hand (bank-pair = x&15).

#define TPB 512
#define PTPB 1024

__device__ __forceinline__ int SW(int x){ return x ^ ((x >> 4) & 15); }

__device__ __forceinline__ float2 cadd(float2 a, float2 b){ return make_float2(a.x+b.x, a.y+b.y); }
__device__ __forceinline__ float2 csub(float2 a, float2 b){ return make_float2(a.x-b.x, a.y-b.y); }
__device__ __forceinline__ float2 cmulf(float2 a, float2 b){
  return make_float2(a.x*b.x - a.y*b.y, a.x*b.y + a.y*b.x);
}
template<int SGN>
__device__ __forceinline__ float2 muli(float2 v){       // SGN*i*v
  return (SGN > 0) ? make_float2(-v.y, v.x) : make_float2(v.y, -v.x);
}

template<int SGN>   // -1: forward DFT8; +1: conj (unscaled inverse)
__device__ __forceinline__ void dft8(const float2* a, float2* X){
  const float C  = 0.70710678118654752f;
  const float SC = (SGN > 0) ? C : -C;
  float2 e0=cadd(a[0],a[4]), e1=csub(a[0],a[4]);
  float2 e2=cadd(a[2],a[6]), e3=csub(a[2],a[6]);
  float2 f0=cadd(a[1],a[5]), f1=csub(a[1],a[5]);
  float2 f2=cadd(a[3],a[7]), f3=csub(a[3],a[7]);
  float2 ie3 = muli<SGN>(e3), if3 = muli<SGN>(f3);
  float2 E0=cadd(e0,e2), E2=csub(e0,e2);
  float2 E1=cadd(e1,ie3), E3=csub(e1,ie3);
  float2 O0=cadd(f0,f2), O2=csub(f0,f2);
  float2 O1=cadd(f1,if3), O3=csub(f1,if3);
  float2 O2r = muli<SGN>(O2);
  float2 O1r = cmulf(O1, make_float2(C,  SC));
  float2 O3r = cmulf(O3, make_float2(-C, SC));
  X[0]=cadd(E0,O0);  X[4]=csub(E0,O0);
  X[1]=cadd(E1,O1r); X[5]=csub(E1,O1r);
  X[2]=cadd(E2,O2r); X[6]=csub(E2,O2r);
  X[3]=cadd(E3,O3r); X[7]=csub(E3,O3r);
}

template<int NFFT, int T>
__device__ void dif8_stage(float2* S, int size, int tid){
  const int t = size >> 3;
  const float ang = -6.283185307179586f / (float)size;
  for (int u = tid; u < (NFFT >> 3); u += T){
    int j = u & (t - 1);
    int base = ((u - j) << 3) + j;
    float2 a[8], X[8];
#pragma unroll
    for (int q = 0; q < 8; q++) a[q] = S[SW(base + q*t)];
    dft8<-1>(a, X);
    if (t > 1){
      float sn, cn; __sincosf(ang * (float)j, &sn, &cn);
      float2 w = make_float2(cn, sn), wq = w;
#pragma unroll
      for (int q = 1; q < 8; q++){ X[q] = cmulf(X[q], wq); wq = cmulf(wq, w); }
    }
#pragma unroll
    for (int q = 0; q < 8; q++) S[SW(base + q*t)] = X[q];
  }
}

template<int NFFT, int T>
__device__ void dit8_stage(float2* S, int size, int tid){
  const int t = size >> 3;
  const float ang = 6.283185307179586f / (float)size;
  for (int u = tid; u < (NFFT >> 3); u += T){
    int j = u & (t - 1);
    int base = ((u - j) << 3) + j;
    float2 a[8], X[8];
#pragma unroll
    for (int q = 0; q < 8; q++) a[q] = S[SW(base + q*t)];
    if (t > 1){
      float sn, cn; __sincosf(ang * (float)j, &sn, &cn);
      float2 w = make_float2(cn, sn), wq = w;
#pragma unroll
      for (int q = 1; q < 8; q++){ a[q] = cmulf(a[q], wq); wq = cmulf(wq, w); }
    }
    dft8<1>(a, X);
#pragma unroll
    for (int q = 0; q < 8; q++) S[SW(base + q*t)] = X[q];
  }
}

// radix-2 on adjacent pairs, via float4. Under SW, logical pair (2f,2f+1) sits
// at float4 index f^((f>>4)&7), halves swapped iff (f>>3)&1 — compensated by sg.
template<int NFFT, int T>
__device__ void r2_stage(float2* S, int tid){
  float4* S4 = reinterpret_cast<float4*>(S);
  for (int f = tid; f < (NFFT >> 1); f += T){
    int V  = (f >> 3) & 15;
    int fp = f ^ (V >> 1);
    float4 v = S4[fp];
    float sg = (V & 1) ? -1.0f : 1.0f;
    float4 r;
    r.x = sg*v.x + v.z;  r.y = sg*v.y + v.w;
    r.z = v.x - sg*v.z;  r.w = v.y - sg*v.w;
    S4[fp] = r;
  }
}

__device__ __forceinline__ int sig8192(int k){
  return ((k & 7) << 10) | (((k >> 3) & 7) << 7) | (((k >> 6) & 7) << 4)
       | (((k >> 9) & 7) << 1) | ((k >> 12) & 1);
}
__device__ __forceinline__ int sig4096(int k){
  return ((k & 7) << 9) | (((k >> 3) & 7) << 6) | (((k >> 6) & 7) << 3) | ((k >> 9) & 7);
}
__device__ __forceinline__ int siginv_even(int m){  // k such that sig8192(k) == 2m
  return (m >> 9) | (((m >> 6) & 7) << 3) | (((m >> 3) & 7) << 6) | ((m & 7) << 9);
}

__global__ void s4_khat_kernel(const float* __restrict__ Bp, const float* __restrict__ Cp,
                               float2* __restrict__ khat){
  int l = blockIdx.x * blockDim.x + threadIdx.x;
  if (l > 4096) return;
  const double PI = 3.14159265358979323846264338327950288;
  double th = (2.0 * PI / 8192.0) * (double)l;
  double wr = cos(th), wi = sin(th);
  double ux = 1.0 + wr, uy = wi;
  double vx = 1.0 - wr, vy = -wi;
  double gx = 20.0 * vx, gy = 20.0 * vy;
  double s00x=0,s00y=0, s01x=0,s01y=0, s10x=0,s10y=0, s11x=0,s11y=0;
  for (int n = 0; n < 64; n++){
    double Bn = (double)Bp[n], Cn = (double)Cp[n];
    double Pn = sqrt((double)n + 0.5);
    double lx = -0.5, ly = PI * (double)n;
    double dx = gx - (ux*lx - uy*ly);
    double dy = gy - (ux*ly + uy*lx);
    double inv2 = 2.0 / (dx*dx + dy*dy);
    double cix = dx * inv2, ciy = -dy * inv2;
    double w00 = Cn*Bn, w01 = Cn*Pn, w10 = Pn*Bn, w11 = Pn*Pn;
    s00x += w00*cix; s00y += w00*ciy;
    s01x += w01*cix; s01y += w01*ciy;
    s10x += w10*cix; s10y += w10*ciy;
    s11x += w11*cix; s11y += w11*ciy;
  }
  double hux = 0.5*ux, huy = 0.5*uy;
  double k11x = hux*s11x - huy*s11y;
  double k11y = hux*s11y + huy*s11x;
  double p1x = 1.0 + k11x, p1y = k11y;
  double t1x = s01x*p1x - s01y*p1y, t1y = s01x*p1y + s01y*p1x;
  double t2x = t1x*s10x - t1y*s10y, t2y = t1x*s10y + t1y*s10x;
  double crx = t2x*hux - t2y*huy,   cry = t2x*huy + t2y*hux;
  khat[l] = make_float2((float)(s00x - crx), (float)(s00y - cry));
}

__global__ __launch_bounds__(PTPB, 4) void s4_prep_kernel(const float2* __restrict__ khat,
                                                          float2* __restrict__ Ta,
                                                          float2* __restrict__ Tb){
  __shared__ __align__(16) float2 S[8192];
  const int tid = threadIdx.x;
  // phase 1: packed spectrum for real IFFT-8192, placed at sigma4096 positions
  for (int k = tid; k < 4096; k += PTPB){
    float2 Yk = khat[k];
    float2 Ymc = khat[4096 - k];
    float2 E  = make_float2(0.5f*(Yk.x + Ymc.x), 0.5f*(Yk.y - Ymc.y));
    float2 Bd = make_float2(0.5f*(Yk.x - Ymc.x), 0.5f*(Yk.y + Ymc.y));
    float sn, cn; __sincosf(7.669903939428206e-4f * (float)k, &sn, &cn);
    float2 O = cmulf(make_float2(cn, sn), Bd);
    S[SW(sig4096(k))] = make_float2((E.x - O.y) * (1.0f/4096.0f),
                                    (E.y + O.x) * (1.0f/4096.0f));
  }
  __syncthreads();
  dit8_stage<4096,PTPB>(S, 8, tid);    __syncthreads();
  dit8_stage<4096,PTPB>(S, 64, tid);   __syncthreads();
  dit8_stage<4096,PTPB>(S, 512, tid);  __syncthreads();
  dit8_stage<4096,PTPB>(S, 4096, tid); __syncthreads();
  // S[SW(n)], n<4096 = K[2n] + i K[2n+1]; zero-pad upper half (SW-closed range)
  for (int n = 4096 + tid; n < 8192; n += PTPB) S[n] = make_float2(0.f, 0.f);
  __syncthreads();
  dif8_stage<8192,PTPB>(S, 8192, tid); __syncthreads();
  dif8_stage<8192,PTPB>(S, 1024, tid); __syncthreads();
  dif8_stage<8192,PTPB>(S, 128, tid);  __syncthreads();
  dif8_stage<8192,PTPB>(S, 16, tid);   __syncthreads();
  r2_stage<8192,PTPB>(S, tid);         __syncthreads();
  // unpack rfft_16384 bins into pre-permuted pair tables (scaled by 1/8192)
  const float sc = 1.0f / 8192.0f;
  for (int m = tid; m < 4097; m += PTPB){
    int s, k;
    if (m == 4096){ s = 1; k = 4096; }           // self-pair k=4096 at odd s=1
    else          { s = 2*m; k = siginv_even(m); }
    int j = (8192 - k) & 8191;
    int sj = sig8192(j);
    float2 Zk = S[SW(s)], Zj = S[SW(sj)];
    float2 A  = make_float2(0.5f*(Zk.x + Zj.x), 0.5f*(Zk.y - Zj.y));
    float2 Bc = make_float2(0.5f*(Zk.x - Zj.x), 0.5f*(Zk.y + Zj.y));
    float sn, cn; __sincosf(-3.834951969714103e-4f * (float)k, &sn, &cn);
    float2 tb  = cmulf(make_float2(cn, sn), Bc);
    float2 tcb = cmulf(make_float2(cn, -sn), make_float2(Bc.x, -Bc.y));
    Ta[m] = make_float2((A.x + tb.y) * sc,  (A.y - tb.x) * sc);   // H[k]/8192
    Tb[m] = make_float2((A.x + tcb.y) * sc, (-A.y - tcb.x) * sc); // H[8192-k]/8192
  }
}

__global__ __launch_bounds__(TPB, 4) void s4_conv_kernel(const float2* __restrict__ x2,
                                                         const float2* __restrict__ Ta,
                                                         const float2* __restrict__ Tb,
                                                         float2* __restrict__ y2){
  __shared__ __align__(16) float2 S[8192];
  const int tid = threadIdx.x;
  const int b = blockIdx.x;
  const float2* xb = x2 + (size_t)b * 4096;
  for (int n = tid; n < 4096; n += TPB) S[SW(n)] = xb[n];
  for (int n = 4096 + tid; n < 8192; n += TPB) S[n] = make_float2(0.f, 0.f);
  __syncthreads();
  dif8_stage<8192,TPB>(S, 8192, tid); __syncthreads();
  dif8_stage<8192,TPB>(S, 1024, tid); __syncthreads();
  dif8_stage<8192,TPB>(S, 128, tid);  __syncthreads();
  dif8_stage<8192,TPB>(S, 16, tid);   __syncthreads();
  r2_stage<8192,TPB>(S, tid);         __syncthreads();
  // pointwise: iterate pairs via their EVEN sigma address (perfect matching,
  // race-free, no barrier needed inside; partner address is always odd)
  for (int m = tid; m < 4097; m += TPB){
    int s, k;
    if (m == 4096){ s = 1; k = 4096; }
    else          { s = 2*m; k = siginv_even(m); }
    int j = (8192 - k) & 8191;
    int sj = sig8192(j);
    int as = SW(s), aj = SW(sj);
    float2 Zk = S[as], Zj = S[aj];
    float2 A  = make_float2(0.5f*(Zk.x + Zj.x), 0.5f*(Zk.y - Zj.y));
    float2 Bc = make_float2(0.5f*(Zk.x - Zj.x), 0.5f*(Zk.y + Zj.y));
    float sn, cn; __sincosf(-3.834951969714103e-4f * (float)k, &sn, &cn);
    float2 tb  = cmulf(make_float2(cn, sn), Bc);
    float2 tcb = cmulf(make_float2(cn, -sn), make_float2(Bc.x, -Bc.y));
    float2 Xk = make_float2(A.x + tb.y,  A.y - tb.x);
    float2 Xm = make_float2(A.x + tcb.y, -A.y - tcb.x);
    float2 Yk = cmulf(Xk, Ta[m]);
    float2 Ym = cmulf(Xm, Tb[m]);
    float2 E = make_float2(0.5f*(Yk.x + Ym.x), 0.5f*(Yk.y - Ym.y));
    float2 D = make_float2(0.5f*(Yk.x - Ym.x), 0.5f*(Yk.y + Ym.y));
    float2 Od = cmulf(make_float2(cn, -sn), D);
    S[as] = make_float2(E.x - Od.y, E.y + Od.x);
    if (aj != as)
      S[aj] = make_float2(E.x + Od.y, Od.x - E.y);
  }
  __syncthreads();
  r2_stage<8192,TPB>(S, tid);         __syncthreads();
  dit8_stage<8192,TPB>(S, 16, tid);   __syncthreads();
  dit8_stage<8192,TPB>(S, 128, tid);  __syncthreads();
  dit8_stage<8192,TPB>(S, 1024, tid); __syncthreads();
  dit8_stage<8192,TPB>(S, 8192, tid); __syncthreads();
  float2* yb = y2 + (size_t)b * 4096;
  for (int n = tid; n < 4096; n += TPB) yb[n] = S[SW(n)];
}

extern "C" void kernel_launch(void* const* d_in, const int* in_sizes, int n_in,
                              void* d_out, int out_size, void* d_ws, size_t ws_size,
                              hipStream_t stream){
  (void)n_in; (void)out_size; (void)ws_size;
  const float* x  = (const float*)d_in[0];
  const float* Bp = (const float*)d_in[1];
  const float* Cp = (const float*)d_in[2];
  // ws: Ta[4097] @0 (32776B), Tb[4097] @33024, khat[4097] @66048  (~96.5 KB)
  float2* Ta   = (float2*)d_ws;
  float2* Tb   = (float2*)((char*)d_ws + 33024);
  float2* khat = (float2*)((char*)d_ws + 66048);
  const int batch = in_sizes[0] / 8192;
  hipLaunchKernelGGL(s4_khat_kernel, dim3(17), dim3(256), 0, stream, Bp, Cp, khat);
  hipLaunchKernelGGL(s4_prep_kernel, dim3(1), dim3(PTPB), 0, stream, khat, Ta, Tb);
  hipLaunchKernelGGL(s4_conv_kernel, dim3(batch), dim3(TPB), 0, stream,
                     (const float2*)x, (const float2*)Ta, (const float2*)Tb, (float2*)d_out);
}